// Round 5
// baseline (290.551 us; speedup 1.0000x reference)
//
#include <hip/hip_runtime.h>
#include <cstdint>
#include <cstddef>

#define DM 1024
#define NH 16
#define DQ 64
#define NB 8
#define LSEQ 1024

typedef __attribute__((ext_vector_type(8))) short short8;
typedef __attribute__((ext_vector_type(4))) float floatx4;

__device__ __forceinline__ unsigned short f2bf(float f) {
  union { float f; unsigned u; } v; v.f = f;
  unsigned r = v.u + 0x7FFFu + ((v.u >> 16) & 1u);
  return (unsigned short)(r >> 16);
}
__device__ __forceinline__ float bf2f(unsigned short u) {
  union { unsigned u; float f; } v; v.u = ((unsigned)u) << 16;
  return v.f;
}

__device__ __forceinline__ void async_load16(const void* g, void* l) {
  __builtin_amdgcn_global_load_lds(
      (const __attribute__((address_space(1))) unsigned int*)g,
      (__attribute__((address_space(3))) unsigned int*)l, 16, 0, 0);
}

// ---------------- convert q,k (f32 -> bf16) ----------------
__global__ void convert_qk(const float* __restrict__ q, const float* __restrict__ k,
                           unsigned short* __restrict__ qb, unsigned short* __restrict__ kb) {
  size_t i = ((size_t)blockIdx.x * 256 + threadIdx.x) * 4;
  float4 a = *(const float4*)&q[i];
  ushort4 r;
  r.x = f2bf(a.x); r.y = f2bf(a.y); r.z = f2bf(a.z); r.w = f2bf(a.w);
  *(ushort4*)&qb[i] = r;
  float4 b = *(const float4*)&k[i];
  ushort4 s;
  s.x = f2bf(b.x); s.y = f2bf(b.y); s.z = f2bf(b.z); s.w = f2bf(b.w);
  *(ushort4*)&kb[i] = s;
}

// ---------------- transpose W (f32 [K][N]) -> Wt (bf16 [N][K]) ----------------
__global__ void transpose_w(const float* __restrict__ Wq, const float* __restrict__ Wk,
                            const float* __restrict__ Wv, unsigned short* __restrict__ Wt) {
  int z = blockIdx.z;
  const float* W = (z == 0) ? Wq : (z == 1) ? Wk : Wv;
  __shared__ float tile[32][33];
  int n0 = blockIdx.x * 32, k0 = blockIdx.y * 32;
  int tx = threadIdx.x;
  for (int j = threadIdx.y; j < 32; j += 8)
    tile[j][tx] = W[(size_t)(k0 + j) * DM + n0 + tx];
  __syncthreads();
  unsigned short* o = Wt + (size_t)z * DM * DM;
  for (int j = threadIdx.y; j < 32; j += 8)
    o[(size_t)(n0 + j) * DM + k0 + tx] = f2bf(tile[tx][j]);
}

// ---------------- projection GEMM + fused masks + V-transpose epilogue ----------------
// grid (64 row, 8 col, 3): id%8 = row%8 -> all col-blocks of a row-strip share an XCD
// BK=64, XOR-swizzled chunk staging (2-way max on fragment b128 reads)
// z<2 epilogue: wave-private LDS transpose -> coalesced int4 stores (WRITE_SIZE 90->50MB, R4 win)
// z==0: Pq pre-scaled by 1/sqrt(DQ)=0.125 (single rounding; attn drops its rescale loop)
__global__ __launch_bounds__(256, 4) void gemm_proj(
    const unsigned short* __restrict__ qb, const unsigned short* __restrict__ kb,
    const unsigned short* __restrict__ Wt,
    const float* __restrict__ bq, const float* __restrict__ bk, const float* __restrict__ bv,
    const float* __restrict__ /*unused*/,
    unsigned short* __restrict__ Pq, unsigned short* __restrict__ Pk,
    unsigned short* __restrict__ Pvt,
    float* __restrict__ qmask, float* __restrict__ kmask) {
  const int z = blockIdx.z;
  const unsigned short* A = (z == 0) ? qb : kb;
  const unsigned short* Bt = Wt + (size_t)z * DM * DM;
  const float* bias = (z == 0) ? bq : (z == 1) ? bk : bv;

  __shared__ unsigned short smem[16384];  // As 128x64, Bs 128x64; epilogue reuses slabs
  unsigned short* As = smem;
  unsigned short* Bs = smem + 8192;

  const int tid = threadIdx.x;
  const int lane = tid & 63;
  const int wave = tid >> 6;
  const int l16 = lane & 15, quad = lane >> 4;
  const int wm = wave & 1, wn = wave >> 1;
  const int rowBase = blockIdx.x * 128;  // row on x -> XCD locality for A
  const int colBase = blockIdx.y * 128;

  floatx4 acc[4][4];
  const floatx4 zf = {0.f, 0.f, 0.f, 0.f};
#pragma unroll
  for (int i = 0; i < 4; i++)
#pragma unroll
    for (int j = 0; j < 4; j++) acc[i][j] = zf;

  const int srl = lane >> 3;
  const int sl7 = lane & 7;

  for (int kt = 0; kt < DM; kt += 64) {
#pragma unroll
    for (int cc = wave; cc < 16; cc += 4) {
      const int rl = cc * 8 + srl;
      const int ck = (sl7 ^ (rl & 7)) * 8;
      async_load16(A + (size_t)(rowBase + rl) * DM + kt + ck, &As[cc * 512]);
      async_load16(Bt + (size_t)(colBase + rl) * DM + kt + ck, &Bs[cc * 512]);
    }
    __syncthreads();

#pragma unroll
    for (int c = 0; c < 2; c++) {
      const int chnk = ((c << 2) + quad) ^ (l16 & 7);
      short8 af[4], bfr[4];
#pragma unroll
      for (int i = 0; i < 4; i++)
        af[i] = *(const short8*)&As[(wm * 64 + i * 16 + l16) * 64 + chnk * 8];
#pragma unroll
      for (int j = 0; j < 4; j++)
        bfr[j] = *(const short8*)&Bs[(wn * 64 + j * 16 + l16) * 64 + chnk * 8];
#pragma unroll
      for (int i = 0; i < 4; i++)
#pragma unroll
        for (int j = 0; j < 4; j++)
          acc[i][j] = __builtin_amdgcn_mfma_f32_16x16x32_bf16(af[i], bfr[j], acc[i][j], 0, 0, 0);
    }
    __syncthreads();
  }

#pragma unroll
  for (int j = 0; j < 4; j++) {
    const float bj = bias[colBase + wn * 64 + j * 16 + l16];
#pragma unroll
    for (int i = 0; i < 4; i++)
#pragma unroll
      for (int r = 0; r < 4; r++) acc[i][j][r] += bj;
  }

  if (z < 2) {
    float* mask = (z == 0) ? qmask : kmask;
    const int h = (colBase >> 6) + wn;
#pragma unroll
    for (int i = 0; i < 4; i++)
#pragma unroll
      for (int r = 0; r < 4; r++) {
        float rs = acc[i][0][r] + acc[i][1][r] + acc[i][2][r] + acc[i][3][r];
        rs += __shfl_xor(rs, 1);
        rs += __shfl_xor(rs, 2);
        rs += __shfl_xor(rs, 4);
        rs += __shfl_xor(rs, 8);
        if (l16 == 0) {
          const int row = rowBase + wm * 64 + i * 16 + quad * 4 + r;
          mask[((size_t)((row >> 10) * NH + h)) * LSEQ + (row & 1023)] = (rs != 0.f) ? 1.f : 0.f;
        }
      }
    // coalesced P write: wave-private LDS slab [32 rows][72], two passes.
    unsigned short* P = (z == 0) ? Pq : Pk;
    const float pscale = (z == 0) ? 0.125f : 1.0f;  // fold 1/sqrt(DQ) into Pq
    const int bb2 = rowBase >> 10;
    const int l0 = (rowBase & 1023) + wm * 64;
    const size_t pbase = ((size_t)(bb2 * NH + h) * LSEQ + l0) * DQ;
    unsigned short* lds = smem + wave * 2304;
#pragma unroll
    for (int pass = 0; pass < 2; ++pass) {
#pragma unroll
      for (int ii = 0; ii < 2; ++ii) {
        const int i = pass * 2 + ii;
#pragma unroll
        for (int j = 0; j < 4; ++j)
#pragma unroll
          for (int r = 0; r < 4; ++r)
            lds[(ii * 16 + quad * 4 + r) * 72 + j * 16 + l16] = f2bf(acc[i][j][r] * pscale);
      }
      asm volatile("s_waitcnt lgkmcnt(0)" ::: "memory");
#pragma unroll
      for (int ll = 0; ll < 4; ++ll) {
        const int c = ll * 8 + (lane >> 3);   // row within pass: 0..31
        const int seg = lane & 7;             // 16B segment within 128B row
        int4 v = *(const int4*)&lds[c * 72 + seg * 8];
        *(int4*)&P[pbase + (size_t)(pass * 32 + c) * DQ + seg * 8] = v;
      }
      if (pass == 0) asm volatile("s_waitcnt lgkmcnt(0)" ::: "memory");
    }
  } else {
    const int b = rowBase >> 10;
    const int l0r = rowBase & 1023;
#pragma unroll
    for (int j = 0; j < 4; j++) {
      __syncthreads();
#pragma unroll
      for (int i = 0; i < 4; i++) {
        ushort4 v;
        v.x = f2bf(acc[i][j][0]); v.y = f2bf(acc[i][j][1]);
        v.z = f2bf(acc[i][j][2]); v.w = f2bf(acc[i][j][3]);
        *(ushort4*)&smem[(wn * 16 + l16) * 136 + wm * 64 + i * 16 + quad * 4] = v;
      }
      __syncthreads();
      const int c = tid >> 3, seg = tid & 7;
      const int col = colBase + (c >> 4) * 64 + j * 16 + (c & 15);
      const int hh = col >> 6, d = col & 63;
      int4 t0 = *(const int4*)&smem[c * 136 + seg * 16];
      int4 t1 = *(const int4*)&smem[c * 136 + seg * 16 + 8];
      const size_t g = ((size_t)((b * NH + hh) * DQ + d)) * LSEQ + l0r + seg * 16;
      *(int4*)&Pvt[g] = t0;
      *(int4*)&Pvt[g + 8] = t1;
    }
  }
}

// ---------------- flash attention v5: L2-direct K/V, barrier-free, per-wave trip count ----
// K/V per bh = 256KB, L2-resident (all 8 qblk blocks of a bh map to one XCD: id%8 = bh%8).
// Staging + double-buffers + ALL __syncthreads removed (Ps slabs are wave-private).
// Fragments read directly from global: each short8 load = 16 rows x 64B, fully coalesced.
__global__ __launch_bounds__(256, 4) void attn_kernel(
    const unsigned short* __restrict__ Q, const unsigned short* __restrict__ K,
    const unsigned short* __restrict__ Vt,  // [b][h][d][l]
    const float* __restrict__ kmask, const float* __restrict__ qmask,
    const float* __restrict__ qin, float* __restrict__ out) {
  const int bh = blockIdx.x;          // id%8 = bh%8 -> all qblks of a bh share an XCD
  const int qblk = 7 - blockIdx.y;    // heavy (long) q-blocks launch first -> better tail
  const int b = bh >> 4, h = bh & 15;
  const size_t base = (size_t)bh * LSEQ * DQ;

  const int tid = threadIdx.x;
  const int lane = tid & 63;
  const int wave = tid >> 6;
  const int l16 = lane & 15, quad = lane >> 4;
  const int qw = qblk * 128 + wave * 32;

  __shared__ unsigned short Ps[4][2304];

  // Q fragments direct (Pq already scaled by 0.125 in gemm_proj)
  short8 qf[2][2];
#pragma unroll
  for (int sub = 0; sub < 2; sub++)
#pragma unroll
    for (int c = 0; c < 2; c++)
      qf[sub][c] = *(const short8*)&Q[base + (size_t)(qw + sub * 16 + l16) * DQ + c * 32 + quad * 8];

  const floatx4 zf = {0.f, 0.f, 0.f, 0.f};
  floatx4 o[2][4];
#pragma unroll
  for (int sub = 0; sub < 2; sub++)
#pragma unroll
    for (int jj = 0; jj < 4; jj++) o[sub][jj] = zf;
  float l_p[2][4] = {{0.f, 0.f, 0.f, 0.f}, {0.f, 0.f, 0.f, 0.f}};

  const int tmax = 2 * qblk + (wave >> 1);  // per-wave causal trip count

  for (int t = 0; t <= tmax; t++) {
    const int kt = t * 64;
    const bool diag = (t == tmax);

    float km[4];
#pragma unroll
    for (int ct = 0; ct < 4; ct++) km[ct] = kmask[(size_t)bh * LSEQ + kt + ct * 16 + l16];

    // K fragments direct from global (L2-hot)
    short8 kf[4][2];
#pragma unroll
    for (int ct = 0; ct < 4; ct++) {
      const unsigned short* kp = &K[base + (size_t)(kt + ct * 16 + l16) * DQ + quad * 8];
      kf[ct][0] = *(const short8*)kp;
      kf[ct][1] = *(const short8*)(kp + 32);
    }

#pragma unroll
    for (int sub = 0; sub < 2; sub++) {
      floatx4 s[4];
#pragma unroll
      for (int ct = 0; ct < 4; ct++) {
        floatx4 sv = zf;
        sv = __builtin_amdgcn_mfma_f32_16x16x32_bf16(qf[sub][0], kf[ct][0], sv, 0, 0, 0);
        sv = __builtin_amdgcn_mfma_f32_16x16x32_bf16(qf[sub][1], kf[ct][1], sv, 0, 0, 0);
        s[ct] = sv;
      }
      const int row0 = qw + sub * 16 + quad * 4;
      unsigned short* pw = &Ps[wave][(sub * 16 + quad * 4) * 72];
      if (diag) {
#pragma unroll
        for (int ct = 0; ct < 4; ct++) {
          const int col = kt + ct * 16 + l16;
#pragma unroll
          for (int r = 0; r < 4; r++) {
            float e = __expf(s[ct][r]) * km[ct];
            e = (col <= row0 + r) ? e : 0.f;
            l_p[sub][r] += e;
            pw[r * 72 + ct * 16 + l16] = f2bf(e);
          }
        }
      } else {
#pragma unroll
        for (int ct = 0; ct < 4; ct++) {
#pragma unroll
          for (int r = 0; r < 4; r++) {
            float e = __expf(s[ct][r]) * km[ct];
            l_p[sub][r] += e;
            pw[r * 72 + ct * 16 + l16] = f2bf(e);
          }
        }
      }
    }

    // V fragments direct from global (issue overlaps the Ps drain)
    short8 vf[4][2];
#pragma unroll
    for (int jj = 0; jj < 4; jj++) {
      const unsigned short* vp = &Vt[base + (size_t)(jj * 16 + l16) * LSEQ + kt + quad * 8];
      vf[jj][0] = *(const short8*)vp;
      vf[jj][1] = *(const short8*)(vp + 32);
    }
    asm volatile("s_waitcnt lgkmcnt(0)" ::: "memory");

    short8 pf[2][2];
#pragma unroll
    for (int sub = 0; sub < 2; sub++) {
      pf[sub][0] = *(const short8*)&Ps[wave][(sub * 16 + l16) * 72 + quad * 8];
      pf[sub][1] = *(const short8*)&Ps[wave][(sub * 16 + l16) * 72 + 32 + quad * 8];
    }
#pragma unroll
    for (int jj = 0; jj < 4; jj++) {
#pragma unroll
      for (int sub = 0; sub < 2; sub++) {
        o[sub][jj] = __builtin_amdgcn_mfma_f32_16x16x32_bf16(pf[sub][0], vf[jj][0], o[sub][jj], 0, 0, 0);
        o[sub][jj] = __builtin_amdgcn_mfma_f32_16x16x32_bf16(pf[sub][1], vf[jj][1], o[sub][jj], 0, 0, 0);
      }
    }
    // Ps reads complete before next iteration's writes (lgkmcnt drained above; MFMA consumed pf)
    asm volatile("s_waitcnt lgkmcnt(0)" ::: "memory");
  }

  const int hd = h * DQ;
#pragma unroll
  for (int sub = 0; sub < 2; sub++)
#pragma unroll
    for (int r = 0; r < 4; r++) {
      float lv = l_p[sub][r];
      lv += __shfl_xor(lv, 1);
      lv += __shfl_xor(lv, 2);
      lv += __shfl_xor(lv, 4);
      lv += __shfl_xor(lv, 8);
      const int row = qw + sub * 16 + quad * 4 + r;
      const float inv = qmask[(size_t)bh * LSEQ + row] / lv;
#pragma unroll
      for (int jj = 0; jj < 4; jj++) {
        const size_t oi = ((size_t)(b * LSEQ + row)) * DM + hd + jj * 16 + l16;
        out[oi] = o[sub][jj][r] * inv + qin[oi];
      }
    }
}

// ---------------- launch ----------------
extern "C" void kernel_launch(void* const* d_in, const int* in_sizes, int n_in,
                              void* d_out, int out_size, void* d_ws, size_t ws_size,
                              hipStream_t stream) {
  const float* q = (const float*)d_in[0];
  const float* k = (const float*)d_in[1];
  const float* Wq = (const float*)d_in[3];
  const float* bq = (const float*)d_in[4];
  const float* Wk = (const float*)d_in[5];
  const float* bk = (const float*)d_in[6];
  const float* Wv = (const float*)d_in[7];
  const float* bv = (const float*)d_in[8];
  float* out = (float*)d_out;

  char* w = (char*)d_ws;
  unsigned short* qb = (unsigned short*)(w + 0);
  unsigned short* kb = (unsigned short*)(w + 16777216);
  unsigned short* Wt = (unsigned short*)(w + 33554432);
  unsigned short* Pq = (unsigned short*)(w + 39845888);
  unsigned short* Pk = (unsigned short*)(w + 56623104);
  unsigned short* Pvt = (unsigned short*)(w + 73400320);
  float* qmask = (float*)(w + 90177536);
  float* kmask = (float*)(w + 90701824);

  convert_qk<<<8192, 256, 0, stream>>>(q, k, qb, kb);
  transpose_w<<<dim3(32, 32, 3), dim3(32, 8), 0, stream>>>(Wq, Wk, Wv, Wt);
  gemm_proj<<<dim3(64, 8, 3), 256, 0, stream>>>(qb, kb, Wt, bq, bk, bv, nullptr,
                                                Pq, Pk, Pvt, qmask, kmask);
  attn_kernel<<<dim3(128, 8), 256, 0, stream>>>(Pq, Pk, Pvt, kmask, qmask, q, out);
}

// Round 6
// 245.801 us; speedup vs baseline: 1.1821x; 1.1821x over previous
//
#include <hip/hip_runtime.h>
#include <cstdint>
#include <cstddef>

#define DM 1024
#define NH 16
#define DQ 64
#define NB 8
#define LSEQ 1024

typedef __attribute__((ext_vector_type(8))) short short8;
typedef __attribute__((ext_vector_type(4))) float floatx4;

__device__ __forceinline__ unsigned short f2bf(float f) {
  union { float f; unsigned u; } v; v.f = f;
  unsigned r = v.u + 0x7FFFu + ((v.u >> 16) & 1u);
  return (unsigned short)(r >> 16);
}
__device__ __forceinline__ float bf2f(unsigned short u) {
  union { unsigned u; float f; } v; v.u = ((unsigned)u) << 16;
  return v.f;
}

__device__ __forceinline__ void async_load16(const void* g, void* l) {
  __builtin_amdgcn_global_load_lds(
      (const __attribute__((address_space(1))) unsigned int*)g,
      (__attribute__((address_space(3))) unsigned int*)l, 16, 0, 0);
}

// ---------------- convert q,k (f32 -> bf16) ----------------
__global__ void convert_qk(const float* __restrict__ q, const float* __restrict__ k,
                           unsigned short* __restrict__ qb, unsigned short* __restrict__ kb) {
  size_t i = ((size_t)blockIdx.x * 256 + threadIdx.x) * 4;
  float4 a = *(const float4*)&q[i];
  ushort4 r;
  r.x = f2bf(a.x); r.y = f2bf(a.y); r.z = f2bf(a.z); r.w = f2bf(a.w);
  *(ushort4*)&qb[i] = r;
  float4 b = *(const float4*)&k[i];
  ushort4 s;
  s.x = f2bf(b.x); s.y = f2bf(b.y); s.z = f2bf(b.z); s.w = f2bf(b.w);
  *(ushort4*)&kb[i] = s;
}

// ---------------- transpose W (f32 [K][N]) -> Wt (bf16 [N][K]) ----------------
__global__ void transpose_w(const float* __restrict__ Wq, const float* __restrict__ Wk,
                            const float* __restrict__ Wv, unsigned short* __restrict__ Wt) {
  int z = blockIdx.z;
  const float* W = (z == 0) ? Wq : (z == 1) ? Wk : Wv;
  __shared__ float tile[32][33];
  int n0 = blockIdx.x * 32, k0 = blockIdx.y * 32;
  int tx = threadIdx.x;
  for (int j = threadIdx.y; j < 32; j += 8)
    tile[j][tx] = W[(size_t)(k0 + j) * DM + n0 + tx];
  __syncthreads();
  unsigned short* o = Wt + (size_t)z * DM * DM;
  for (int j = threadIdx.y; j < 32; j += 8)
    o[(size_t)(n0 + j) * DM + k0 + tx] = f2bf(tile[tx][j]);
}

// ---------------- projection GEMM + fused masks + V-transpose epilogue ----------------
// grid (64 row, 8 col, 3): id%8 = row%8 -> all col-blocks of a row-strip share an XCD
// BK=64, XOR-swizzled chunk staging (2-way max on fragment b128 reads)
// z<2 epilogue: wave-private LDS transpose -> coalesced int4 stores (WRITE_SIZE 90->50MB, R4 win)
// z==0: Pq pre-scaled by 1/sqrt(DQ)=0.125 (single rounding; attn has no rescale loop)
__global__ __launch_bounds__(256, 4) void gemm_proj(
    const unsigned short* __restrict__ qb, const unsigned short* __restrict__ kb,
    const unsigned short* __restrict__ Wt,
    const float* __restrict__ bq, const float* __restrict__ bk, const float* __restrict__ bv,
    const float* __restrict__ /*unused*/,
    unsigned short* __restrict__ Pq, unsigned short* __restrict__ Pk,
    unsigned short* __restrict__ Pvt,
    float* __restrict__ qmask, float* __restrict__ kmask) {
  const int z = blockIdx.z;
  const unsigned short* A = (z == 0) ? qb : kb;
  const unsigned short* Bt = Wt + (size_t)z * DM * DM;
  const float* bias = (z == 0) ? bq : (z == 1) ? bk : bv;

  __shared__ unsigned short smem[16384];  // As 128x64, Bs 128x64; epilogue reuses slabs
  unsigned short* As = smem;
  unsigned short* Bs = smem + 8192;

  const int tid = threadIdx.x;
  const int lane = tid & 63;
  const int wave = tid >> 6;
  const int l16 = lane & 15, quad = lane >> 4;
  const int wm = wave & 1, wn = wave >> 1;
  const int rowBase = blockIdx.x * 128;  // row on x -> XCD locality for A
  const int colBase = blockIdx.y * 128;

  floatx4 acc[4][4];
  const floatx4 zf = {0.f, 0.f, 0.f, 0.f};
#pragma unroll
  for (int i = 0; i < 4; i++)
#pragma unroll
    for (int j = 0; j < 4; j++) acc[i][j] = zf;

  const int srl = lane >> 3;
  const int sl7 = lane & 7;

  for (int kt = 0; kt < DM; kt += 64) {
#pragma unroll
    for (int cc = wave; cc < 16; cc += 4) {
      const int rl = cc * 8 + srl;
      const int ck = (sl7 ^ (rl & 7)) * 8;
      async_load16(A + (size_t)(rowBase + rl) * DM + kt + ck, &As[cc * 512]);
      async_load16(Bt + (size_t)(colBase + rl) * DM + kt + ck, &Bs[cc * 512]);
    }
    __syncthreads();

#pragma unroll
    for (int c = 0; c < 2; c++) {
      const int chnk = ((c << 2) + quad) ^ (l16 & 7);
      short8 af[4], bfr[4];
#pragma unroll
      for (int i = 0; i < 4; i++)
        af[i] = *(const short8*)&As[(wm * 64 + i * 16 + l16) * 64 + chnk * 8];
#pragma unroll
      for (int j = 0; j < 4; j++)
        bfr[j] = *(const short8*)&Bs[(wn * 64 + j * 16 + l16) * 64 + chnk * 8];
#pragma unroll
      for (int i = 0; i < 4; i++)
#pragma unroll
        for (int j = 0; j < 4; j++)
          acc[i][j] = __builtin_amdgcn_mfma_f32_16x16x32_bf16(af[i], bfr[j], acc[i][j], 0, 0, 0);
    }
    __syncthreads();
  }

#pragma unroll
  for (int j = 0; j < 4; j++) {
    const float bj = bias[colBase + wn * 64 + j * 16 + l16];
#pragma unroll
    for (int i = 0; i < 4; i++)
#pragma unroll
      for (int r = 0; r < 4; r++) acc[i][j][r] += bj;
  }

  if (z < 2) {
    float* mask = (z == 0) ? qmask : kmask;
    const int h = (colBase >> 6) + wn;
#pragma unroll
    for (int i = 0; i < 4; i++)
#pragma unroll
      for (int r = 0; r < 4; r++) {
        float rs = acc[i][0][r] + acc[i][1][r] + acc[i][2][r] + acc[i][3][r];
        rs += __shfl_xor(rs, 1);
        rs += __shfl_xor(rs, 2);
        rs += __shfl_xor(rs, 4);
        rs += __shfl_xor(rs, 8);
        if (l16 == 0) {
          const int row = rowBase + wm * 64 + i * 16 + quad * 4 + r;
          mask[((size_t)((row >> 10) * NH + h)) * LSEQ + (row & 1023)] = (rs != 0.f) ? 1.f : 0.f;
        }
      }
    // coalesced P write: wave-private LDS slab [32 rows][72], two passes.
    unsigned short* P = (z == 0) ? Pq : Pk;
    const float pscale = (z == 0) ? 0.125f : 1.0f;  // fold 1/sqrt(DQ) into Pq
    const int bb2 = rowBase >> 10;
    const int l0 = (rowBase & 1023) + wm * 64;
    const size_t pbase = ((size_t)(bb2 * NH + h) * LSEQ + l0) * DQ;
    unsigned short* lds = smem + wave * 2304;
#pragma unroll
    for (int pass = 0; pass < 2; ++pass) {
#pragma unroll
      for (int ii = 0; ii < 2; ++ii) {
        const int i = pass * 2 + ii;
#pragma unroll
        for (int j = 0; j < 4; ++j)
#pragma unroll
          for (int r = 0; r < 4; ++r)
            lds[(ii * 16 + quad * 4 + r) * 72 + j * 16 + l16] = f2bf(acc[i][j][r] * pscale);
      }
      asm volatile("s_waitcnt lgkmcnt(0)" ::: "memory");
#pragma unroll
      for (int ll = 0; ll < 4; ++ll) {
        const int c = ll * 8 + (lane >> 3);   // row within pass: 0..31
        const int seg = lane & 7;             // 16B segment within 128B row
        int4 v = *(const int4*)&lds[c * 72 + seg * 8];
        *(int4*)&P[pbase + (size_t)(pass * 32 + c) * DQ + seg * 8] = v;
      }
      if (pass == 0) asm volatile("s_waitcnt lgkmcnt(0)" ::: "memory");
    }
  } else {
    const int b = rowBase >> 10;
    const int l0r = rowBase & 1023;
#pragma unroll
    for (int j = 0; j < 4; j++) {
      __syncthreads();
#pragma unroll
      for (int i = 0; i < 4; i++) {
        ushort4 v;
        v.x = f2bf(acc[i][j][0]); v.y = f2bf(acc[i][j][1]);
        v.z = f2bf(acc[i][j][2]); v.w = f2bf(acc[i][j][3]);
        *(ushort4*)&smem[(wn * 16 + l16) * 136 + wm * 64 + i * 16 + quad * 4] = v;
      }
      __syncthreads();
      const int c = tid >> 3, seg = tid & 7;
      const int col = colBase + (c >> 4) * 64 + j * 16 + (c & 15);
      const int hh = col >> 6, d = col & 63;
      int4 t0 = *(const int4*)&smem[c * 136 + seg * 16];
      int4 t1 = *(const int4*)&smem[c * 136 + seg * 16 + 8];
      const size_t g = ((size_t)((b * NH + hh) * DQ + d)) * LSEQ + l0r + seg * 16;
      *(int4*)&Pvt[g] = t0;
      *(int4*)&Pvt[g + 8] = t1;
    }
  }
}

// ---------------- flash attention v4 (restored): dbuf LDS staging, XCD-local bh ----------------
// R5 lesson: direct L2 loads put 16 blocking loads on the critical path per tile (MfmaUtil 8%).
// The global_load_lds double-buffer prefetches tile t+1 under tile t's compute — keep it.
// Q loads are unscaled: Pq is pre-scaled by 0.125 in gemm_proj.
__global__ __launch_bounds__(256, 4) void attn_kernel(
    const unsigned short* __restrict__ Q, const unsigned short* __restrict__ K,
    const unsigned short* __restrict__ Vt,  // [b][h][d][l]
    const float* __restrict__ kmask, const float* __restrict__ qmask,
    const float* __restrict__ qin, float* __restrict__ out) {
  const int bh = blockIdx.x;          // id%8 = bh%8 -> all qblks of a bh share an XCD
  const int qblk = 7 - blockIdx.y;    // heavy (long) q-blocks launch first -> better tail
  const int b = bh >> 4, h = bh & 15;
  const size_t base = (size_t)bh * LSEQ * DQ;

  const int tid = threadIdx.x;
  const int lane = tid & 63;
  const int wave = tid >> 6;
  const int l16 = lane & 15, quad = lane >> 4;
  const int qw = qblk * 128 + wave * 32;

  __shared__ unsigned short Ks[2 * 4096];
  __shared__ unsigned short Vs[2 * 4096];
  __shared__ unsigned short Ps[4][2304];

  short8 qf[2][2];
#pragma unroll
  for (int sub = 0; sub < 2; sub++)
#pragma unroll
    for (int c = 0; c < 2; c++)
      qf[sub][c] = *(const short8*)&Q[base + (size_t)(qw + sub * 16 + l16) * DQ + c * 32 + quad * 8];

  const floatx4 zf = {0.f, 0.f, 0.f, 0.f};
  floatx4 o[2][4];
#pragma unroll
  for (int sub = 0; sub < 2; sub++)
#pragma unroll
    for (int jj = 0; jj < 4; jj++) o[sub][jj] = zf;
  float l_p[2][4] = {{0.f, 0.f, 0.f, 0.f}, {0.f, 0.f, 0.f, 0.f}};

  const int swz = (quad ^ (l16 & 7)) * 8;
  const int swz2 = ((quad + 4) ^ (l16 & 7)) * 8;
  const int vswz = (quad ^ (l16 >> 1)) * 8;
  const int vswz2 = ((quad + 4) ^ (l16 >> 1)) * 8;

  const int srl = (lane >> 3);
  const int ktiles = (qblk + 1) * 2;
  const int tmax = 2 * qblk + (wave >> 1);

  {
#pragma unroll
    for (int cc = wave; cc < 8; cc += 4) {
      const int rl = cc * 8 + srl;
      const int ck = ((lane & 7) ^ (rl & 7)) * 8;
      async_load16(&K[base + (size_t)rl * DQ + ck], &Ks[cc * 512]);
      const int cv = ((lane & 7) ^ ((rl >> 1) & 7)) * 8;
      async_load16(&Vt[base + (size_t)rl * LSEQ + cv], &Vs[cc * 512]);
    }
  }
  __syncthreads();

  for (int t = 0; t < ktiles; t++) {
    const int cur = t & 1;
    const int kt = t * 64;
    const bool live = (t <= tmax);

    float km[4];
    if (live) {
#pragma unroll
      for (int ct = 0; ct < 4; ct++) km[ct] = kmask[(size_t)bh * LSEQ + kt + ct * 16 + l16];
    }

    if (t + 1 < ktiles) {
      const int nkt = kt + 64;
      const int nb = (cur ^ 1) * 4096;
#pragma unroll
      for (int cc = wave; cc < 8; cc += 4) {
        const int rl = cc * 8 + srl;
        const int ck = ((lane & 7) ^ (rl & 7)) * 8;
        async_load16(&K[base + (size_t)(nkt + rl) * DQ + ck], &Ks[nb + cc * 512]);
        const int cv = ((lane & 7) ^ ((rl >> 1) & 7)) * 8;
        async_load16(&Vt[base + (size_t)rl * LSEQ + nkt + cv], &Vs[nb + cc * 512]);
      }
    }

    if (live) {
      const unsigned short* Kb = &Ks[cur * 4096];
      const unsigned short* Vb = &Vs[cur * 4096];
      const bool diag = (t == tmax);

#pragma unroll
      for (int sub = 0; sub < 2; sub++) {
        floatx4 s[4];
#pragma unroll
        for (int ct = 0; ct < 4; ct++) {
          const int kr = (ct * 16 + l16) * 64;
          const short8 kf0 = *(const short8*)&Kb[kr + swz];
          const short8 kf1 = *(const short8*)&Kb[kr + swz2];
          floatx4 sv = zf;
          sv = __builtin_amdgcn_mfma_f32_16x16x32_bf16(qf[sub][0], kf0, sv, 0, 0, 0);
          sv = __builtin_amdgcn_mfma_f32_16x16x32_bf16(qf[sub][1], kf1, sv, 0, 0, 0);
          s[ct] = sv;
        }
        const int row0 = qw + sub * 16 + quad * 4;
        unsigned short* pw = &Ps[wave][(sub * 16 + quad * 4) * 72];
        if (diag) {
#pragma unroll
          for (int ct = 0; ct < 4; ct++) {
            const int col = kt + ct * 16 + l16;
#pragma unroll
            for (int r = 0; r < 4; r++) {
              float e = __expf(s[ct][r]) * km[ct];
              e = (col <= row0 + r) ? e : 0.f;
              l_p[sub][r] += e;
              pw[r * 72 + ct * 16 + l16] = f2bf(e);
            }
          }
        } else {
#pragma unroll
          for (int ct = 0; ct < 4; ct++) {
#pragma unroll
            for (int r = 0; r < 4; r++) {
              float e = __expf(s[ct][r]) * km[ct];
              l_p[sub][r] += e;
              pw[r * 72 + ct * 16 + l16] = f2bf(e);
            }
          }
        }
      }
      asm volatile("s_waitcnt lgkmcnt(0)" ::: "memory");

      short8 pf[2][2];
#pragma unroll
      for (int sub = 0; sub < 2; sub++) {
        pf[sub][0] = *(const short8*)&Ps[wave][(sub * 16 + l16) * 72 + quad * 8];
        pf[sub][1] = *(const short8*)&Ps[wave][(sub * 16 + l16) * 72 + 32 + quad * 8];
      }
#pragma unroll
      for (int jj = 0; jj < 4; jj++) {
        const int vr = (jj * 16 + l16) * 64;
        const short8 vf0 = *(const short8*)&Vb[vr + vswz];
        const short8 vf1 = *(const short8*)&Vb[vr + vswz2];
#pragma unroll
        for (int sub = 0; sub < 2; sub++) {
          o[sub][jj] = __builtin_amdgcn_mfma_f32_16x16x32_bf16(pf[sub][0], vf0, o[sub][jj], 0, 0, 0);
          o[sub][jj] = __builtin_amdgcn_mfma_f32_16x16x32_bf16(pf[sub][1], vf1, o[sub][jj], 0, 0, 0);
        }
      }
    }
    __syncthreads();
  }

  const int hd = h * DQ;
#pragma unroll
  for (int sub = 0; sub < 2; sub++)
#pragma unroll
    for (int r = 0; r < 4; r++) {
      float lv = l_p[sub][r];
      lv += __shfl_xor(lv, 1);
      lv += __shfl_xor(lv, 2);
      lv += __shfl_xor(lv, 4);
      lv += __shfl_xor(lv, 8);
      const int row = qw + sub * 16 + quad * 4 + r;
      const float inv = qmask[(size_t)bh * LSEQ + row] / lv;
#pragma unroll
      for (int jj = 0; jj < 4; jj++) {
        const size_t oi = ((size_t)(b * LSEQ + row)) * DM + hd + jj * 16 + l16;
        out[oi] = o[sub][jj][r] * inv + qin[oi];
      }
    }
}

// ---------------- launch ----------------
extern "C" void kernel_launch(void* const* d_in, const int* in_sizes, int n_in,
                              void* d_out, int out_size, void* d_ws, size_t ws_size,
                              hipStream_t stream) {
  const float* q = (const float*)d_in[0];
  const float* k = (const float*)d_in[1];
  const float* Wq = (const float*)d_in[3];
  const float* bq = (const float*)d_in[4];
  const float* Wk = (const float*)d_in[5];
  const float* bk = (const float*)d_in[6];
  const float* Wv = (const float*)d_in[7];
  const float* bv = (const float*)d_in[8];
  float* out = (float*)d_out;

  char* w = (char*)d_ws;
  unsigned short* qb = (unsigned short*)(w + 0);
  unsigned short* kb = (unsigned short*)(w + 16777216);
  unsigned short* Wt = (unsigned short*)(w + 33554432);
  unsigned short* Pq = (unsigned short*)(w + 39845888);
  unsigned short* Pk = (unsigned short*)(w + 56623104);
  unsigned short* Pvt = (unsigned short*)(w + 73400320);
  float* qmask = (float*)(w + 90177536);
  float* kmask = (float*)(w + 90701824);

  convert_qk<<<8192, 256, 0, stream>>>(q, k, qb, kb);
  transpose_w<<<dim3(32, 32, 3), dim3(32, 8), 0, stream>>>(Wq, Wk, Wv, Wt);
  gemm_proj<<<dim3(64, 8, 3), 256, 0, stream>>>(qb, kb, Wt, bq, bk, bv, nullptr,
                                                Pq, Pk, Pvt, qmask, kmask);
  attn_kernel<<<dim3(128, 8), 256, 0, stream>>>(Pq, Pk, Pvt, kmask, qmask, q, out);
}